// Round 2
// baseline (65.060 us; speedup 1.0000x reference)
//
#include <hip/hip_runtime.h>
#include <hip/hip_bf16.h>
#include <cstdint>

#define BB 64
#define CC 256
#define EPSF 1e-5f
#define PLANES 4

// ---------------------------------------------------------------------------
// Bit-exact replication of the reference float32 bound arithmetic for ONE
// (bank, i, j) cell. No FMA contraction (__f*_rn), floorf, int32 truncation.
// bank 0 = subj(bbox_s), 1 = subj(bbox_o), 2 = joint(clip bbox_s),
// 3 = joint(clip bbox_o).
// ---------------------------------------------------------------------------
__device__ __forceinline__ void region_bounds(int bank, int i, int j,
                                              float sy0, float sy1, float sx0, float sx1,
                                              float oy0, float oy1, float ox0, float ox1,
                                              int& r0, int& r1, int& c0, int& c1) {
    float fi = (float)i, fj = (float)j;
    if (bank < 2) {
        float y0 = bank ? oy0 : sy0, y1 = bank ? oy1 : sy1;
        float x0 = bank ? ox0 : sx0, x1 = bank ? ox1 : sx1;
        float ch = __fdiv_rn(__fsub_rn(y1, y0), 3.0f);
        float cw = __fdiv_rn(__fsub_rn(x1, x0), 3.0f);
        int R0 = (int)floorf(__fmul_rn(64.0f, __fadd_rn(y0, __fmul_rn(fi, ch))));
        int R1 = (int)floorf(__fmul_rn(64.0f, __fadd_rn(y0, __fmul_rn(__fadd_rn(fi, 1.0f), ch))));
        bool dr = (R1 <= R0);
        r1 = (dr && (R1 < 63)) ? R1 + 1 : R1;
        r0 = (dr && (R1 >= 63)) ? R0 - 1 : R0;
        int C0 = (int)floorf(__fmul_rn(64.0f, __fadd_rn(x0, __fmul_rn(fj, cw))));
        int C1 = (int)floorf(__fmul_rn(64.0f, __fadd_rn(x0, __fmul_rn(__fadd_rn(fj, 1.0f), cw))));
        bool dc = (C1 <= C0);
        c1 = (dc && (C1 < 64)) ? C1 + 1 : C1;
        c0 = (dc && (C1 >= 64)) ? C0 - 1 : C0;
    } else {
        float by0 = (bank == 2) ? sy0 : oy0, by1 = (bank == 2) ? sy1 : oy1;
        float bx0 = (bank == 2) ? sx0 : ox0, bx1 = (bank == 2) ? sx1 : ox1;
        float uy0 = fminf(sy0, oy0), uy1 = fmaxf(sy1, oy1);
        float ux0 = fminf(sx0, ox0), ux1 = fmaxf(sx1, ox1);
        float ch = __fdiv_rn(__fsub_rn(uy1, uy0), 3.0f);
        float cw = __fdiv_rn(__fsub_rn(ux1, ux0), 3.0f);
        float ylo = __fadd_rn(uy0, __fmul_rn(fi, ch));
        float yhi = __fadd_rn(uy0, __fmul_rn(__fadd_rn(fi, 1.0f), ch));
        float xlo = __fadd_rn(ux0, __fmul_rn(fj, cw));
        float xhi = __fadd_rn(ux0, __fmul_rn(__fadd_rn(fj, 1.0f), cw));
        r0 = (int)floorf(__fmul_rn(64.0f, fmaxf(by0, ylo)));
        r1 = (int)floorf(__fmul_rn(64.0f, fminf(by1, yhi)));
        c0 = (int)floorf(__fmul_rn(64.0f, fmaxf(bx0, xlo)));
        c1 = (int)floorf(__fmul_rn(64.0f, fminf(bx1, xhi)));
    }
}

// ---------------------------------------------------------------------------
// Kernel 1: per-(b,c) plane 2D prefix sum in LDS -> 36 region sums.
// One wave per block; each block processes PLANES consecutive planes with a
// register double-buffer so the next plane's 16 float4 loads are in flight
// during the current plane's row scan. [64][65] padding keeps both scan
// phases bank-conflict-free (65 mod 32 == 1).
// Bounds are computed inline per-lane (bit-exact); no k_bounds kernel.
// M layout: [b][c][36] raw region SUMS (head divides by cnt).
// ---------------------------------------------------------------------------
__global__ __launch_bounds__(64) void k_region_sums(const float* __restrict__ feat,
                                                    const float* __restrict__ bbox_s,
                                                    const float* __restrict__ bbox_o,
                                                    float* __restrict__ M) {
    int blk = blockIdx.x;
    int l = threadIdx.x;
    int pid0 = blk * PLANES;
    int b = pid0 >> 8;

    float sy0 = bbox_s[b * 4 + 0], sy1 = bbox_s[b * 4 + 1];
    float sx0 = bbox_s[b * 4 + 2], sx1 = bbox_s[b * 4 + 3];
    float oy0 = bbox_o[b * 4 + 0], oy1 = bbox_o[b * 4 + 1];
    float ox0 = bbox_o[b * 4 + 2], ox1 = bbox_o[b * 4 + 3];

    int rl = 0, rh = 0, cl = 0, chh = 0;
    if (l < 36) {
        int bank = l / 9, ij = l % 9, i = ij / 3, j = ij % 3;
        int r0, r1, c0, c1;
        region_bounds(bank, i, j, sy0, sy1, sx0, sx1, oy0, oy1, ox0, ox1, r0, r1, c0, c1);
        rl = max(r0, 0); rh = min(r1, 64);
        cl = max(c0, 0); chh = min(c1, 64);
    }

    __shared__ float S[64 * 65];
    const float4* src = (const float4*)feat + (size_t)pid0 * 1024;

    float4 ra[16], rb[16];

#define LOADP(R, P)                                                         \
    {                                                                       \
        const float4* s2 = src + (size_t)(P) * 1024;                        \
        _Pragma("unroll")                                                   \
        for (int it = 0; it < 16; ++it) R[it] = s2[it * 64 + l];            \
    }

#define STOREP(R)                                                           \
    {                                                                       \
        _Pragma("unroll")                                                   \
        for (int it = 0; it < 16; ++it) {                                   \
            int f = it * 256 + l * 4;                                       \
            int h = f >> 6, w = f & 63;                                     \
            float* dst = &S[h * 65 + w];                                    \
            dst[0] = R[it].x; dst[1] = R[it].y;                             \
            dst[2] = R[it].z; dst[3] = R[it].w;                             \
        }                                                                   \
    }

#define ROWSCAN()                                                           \
    {                                                                       \
        float run = 0.0f; int base = l * 65;                                \
        _Pragma("unroll 16")                                                \
        for (int i = 0; i < 64; ++i) { run += S[base + i]; S[base + i] = run; } \
    }

#define COLSCAN()                                                           \
    {                                                                       \
        float run = 0.0f;                                                   \
        _Pragma("unroll 16")                                                \
        for (int i = 0; i < 64; ++i) { run += S[i * 65 + l]; S[i * 65 + l] = run; } \
    }

#define EVALP(P)                                                            \
    if (l < 36) {                                                           \
        float s = 0.0f;                                                     \
        if (rh > rl && chh > cl) {                                          \
            float a2 = S[(rh - 1) * 65 + (chh - 1)];                        \
            float q  = (cl > 0) ? S[(rh - 1) * 65 + (cl - 1)] : 0.0f;       \
            float pp = (rl > 0) ? S[(rl - 1) * 65 + (chh - 1)] : 0.0f;      \
            float dd = (rl > 0 && cl > 0) ? S[(rl - 1) * 65 + (cl - 1)] : 0.0f; \
            s = a2 - q - pp + dd;                                           \
        }                                                                   \
        M[((size_t)(pid0 + (P))) * 36 + l] = s;                             \
    }

    // plane p body: barrier (prev eval done) -> store -> barrier -> issue
    // prefetch (flies during row scan) -> row scan -> barrier -> col scan
    // -> barrier -> eval
#define PLANE(CUR, NXT, P, PREFETCH)                                        \
    __syncthreads();                                                        \
    STOREP(CUR);                                                            \
    __syncthreads();                                                        \
    if (PREFETCH) LOADP(NXT, (P) + 1);                                      \
    ROWSCAN();                                                              \
    __syncthreads();                                                        \
    COLSCAN();                                                              \
    __syncthreads();                                                        \
    EVALP(P);

    LOADP(ra, 0);
    PLANE(ra, rb, 0, 1);
    PLANE(rb, ra, 1, 1);
    PLANE(ra, rb, 2, 1);
    PLANE(rb, ra, 3, 0);

#undef LOADP
#undef STOREP
#undef ROWSCAN
#undef COLSCAN
#undef EVALP
#undef PLANE
}

// ---------------------------------------------------------------------------
// Kernel 2: head. One block per b. Stage M[b] (256x36) in LDS (pad 37),
// 324 threads each dot 256 channels with conv_w row, BN2 + zero-count mask
// (counts computed inline, bit-exact), fold 4 banks -> f[81], 81->40->9 MLP,
// predicate dot.
// ---------------------------------------------------------------------------
__global__ __launch_bounds__(384) void k_head(const float* __restrict__ M,
                                              const float* __restrict__ bbox_s,
                                              const float* __restrict__ bbox_o,
                                              const float* __restrict__ conv_w,
                                              const float* __restrict__ conv_b,
                                              const float* __restrict__ g2,
                                              const float* __restrict__ b2,
                                              const float* __restrict__ m2,
                                              const float* __restrict__ v2,
                                              const float* __restrict__ fc1_w,
                                              const float* __restrict__ fc1_b,
                                              const float* __restrict__ g1,
                                              const float* __restrict__ b1,
                                              const float* __restrict__ m1,
                                              const float* __restrict__ v1,
                                              const float* __restrict__ fc2_w,
                                              const float* __restrict__ fc2_b,
                                              const float* __restrict__ pred,
                                              float* __restrict__ out) {
    int b = blockIdx.x;
    int t = threadIdx.x;

    __shared__ float Ml[256 * 37];
    __shared__ float val[324];
    __shared__ float fv[81];
    __shared__ float hv[40];
    __shared__ float lg[9];

    for (int i = t; i < 256 * 36; i += 384) {
        int c = i / 36, r = i - c * 36;
        Ml[c * 37 + r] = M[(size_t)b * (256 * 36) + i];
    }
    __syncthreads();

    if (t < 324) {
        int region = t / 9, k = t - region * 9;
        int bank = region / 9, ij = region - bank * 9;
        int ii = ij / 3, jj = ij % 3;
        int o = bank * 81 + ii * 27 + jj * 9 + k;

        float sy0 = bbox_s[b * 4 + 0], sy1 = bbox_s[b * 4 + 1];
        float sx0 = bbox_s[b * 4 + 2], sx1 = bbox_s[b * 4 + 3];
        float oy0 = bbox_o[b * 4 + 0], oy1 = bbox_o[b * 4 + 1];
        float ox0 = bbox_o[b * 4 + 2], ox1 = bbox_o[b * 4 + 3];
        int r0, r1, c0, c1;
        region_bounds(bank, ii, jj, sy0, sy1, sx0, sx1, oy0, oy1, ox0, ox1, r0, r1, c0, c1);
        int nrows = max(0, min(r1, 64) - max(r0, 0));
        int ncols = max(0, min(c1, 64) - max(c0, 0));
        float cnt = (float)(nrows * ncols);

        float v = 0.0f;
        if (cnt > 0.0f) {
            const float* w = conv_w + o * 256;
            float dot = 0.0f;
            #pragma unroll 8
            for (int c = 0; c < 256; ++c) dot += w[c] * Ml[c * 37 + region];
            float mean = dot / cnt;
            float sc = g2[o] / sqrtf(v2[o] + EPSF);
            v = (mean + conv_b[o] - m2[o]) * sc + b2[o];
        }
        val[region * 9 + k] = v;
    }
    __syncthreads();

    if (t < 81) {
        int k = t / 9, ij = t - k * 9;
        fv[t] = val[(0 + ij) * 9 + k] + val[(9 + ij) * 9 + k] +
                val[(18 + ij) * 9 + k] + val[(27 + ij) * 9 + k];
    }
    __syncthreads();

    if (t < 40) {
        float h = fc1_b[t];
        for (int u = 0; u < 81; ++u) h += fv[u] * fc1_w[t * 81 + u];
        h = (h - m1[t]) * (g1[t] / sqrtf(v1[t] + EPSF)) + b1[t];
        hv[t] = h;
    }
    __syncthreads();

    if (t < 9) {
        float lgt = fc2_b[t];
        for (int u = 0; u < 40; ++u) lgt += hv[u] * fc2_w[t * 40 + u];
        lg[t] = lgt * pred[b * 9 + t];
    }
    __syncthreads();

    if (t == 0) {
        float s = 0.0f;
        for (int i = 0; i < 9; ++i) s += lg[i];
        out[b] = s;
    }
}

extern "C" void kernel_launch(void* const* d_in, const int* in_sizes, int n_in,
                              void* d_out, int out_size, void* d_ws, size_t ws_size,
                              hipStream_t stream) {
    const float* feat   = (const float*)d_in[0];
    const float* bbox_s = (const float*)d_in[1];
    const float* bbox_o = (const float*)d_in[2];
    const float* pred   = (const float*)d_in[3];
    const float* conv_w = (const float*)d_in[4];
    const float* conv_b = (const float*)d_in[5];
    const float* g2     = (const float*)d_in[6];
    const float* b2     = (const float*)d_in[7];
    const float* m2     = (const float*)d_in[8];
    const float* v2     = (const float*)d_in[9];
    const float* fc1_w  = (const float*)d_in[10];
    const float* fc1_b  = (const float*)d_in[11];
    const float* g1     = (const float*)d_in[12];
    const float* b1     = (const float*)d_in[13];
    const float* m1     = (const float*)d_in[14];
    const float* v1     = (const float*)d_in[15];
    const float* fc2_w  = (const float*)d_in[16];
    const float* fc2_b  = (const float*)d_in[17];
    float* out = (float*)d_out;

    float* M = (float*)d_ws;  // 64*256*36*4 = 2359296 B

    k_region_sums<<<(BB * CC) / PLANES, 64, 0, stream>>>(feat, bbox_s, bbox_o, M);
    k_head<<<BB, 384, 0, stream>>>(M, bbox_s, bbox_o, conv_w, conv_b, g2, b2, m2, v2,
                                   fc1_w, fc1_b, g1, b1, m1, v1, fc2_w, fc2_b,
                                   pred, out);
}

// Round 3
// 63.017 us; speedup vs baseline: 1.0324x; 1.0324x over previous
//
#include <hip/hip_runtime.h>
#include <hip/hip_bf16.h>
#include <cstdint>

#define BB 64
#define CC 256
#define EPSF 1e-5f
#define PLANES 4
#define ZROW 24
#define SSTR 65  // snapshot row stride in dwords (65 mod 32 = 1 spreads rows across banks)

// ---------------------------------------------------------------------------
// Bit-exact replication of the reference float32 bound arithmetic for ONE
// (bank, i, j) cell. No FMA contraction (__f*_rn), floorf, int32 truncation.
// bank 0 = subj(bbox_s), 1 = subj(bbox_o), 2 = joint(clip bbox_s),
// 3 = joint(clip bbox_o).
// ---------------------------------------------------------------------------
__device__ __forceinline__ void region_bounds(int bank, int i, int j,
                                              float sy0, float sy1, float sx0, float sx1,
                                              float oy0, float oy1, float ox0, float ox1,
                                              int& r0, int& r1, int& c0, int& c1) {
    float fi = (float)i, fj = (float)j;
    if (bank < 2) {
        float y0 = bank ? oy0 : sy0, y1 = bank ? oy1 : sy1;
        float x0 = bank ? ox0 : sx0, x1 = bank ? ox1 : sx1;
        float ch = __fdiv_rn(__fsub_rn(y1, y0), 3.0f);
        float cw = __fdiv_rn(__fsub_rn(x1, x0), 3.0f);
        int R0 = (int)floorf(__fmul_rn(64.0f, __fadd_rn(y0, __fmul_rn(fi, ch))));
        int R1 = (int)floorf(__fmul_rn(64.0f, __fadd_rn(y0, __fmul_rn(__fadd_rn(fi, 1.0f), ch))));
        bool dr = (R1 <= R0);
        r1 = (dr && (R1 < 63)) ? R1 + 1 : R1;
        r0 = (dr && (R1 >= 63)) ? R0 - 1 : R0;
        int C0 = (int)floorf(__fmul_rn(64.0f, __fadd_rn(x0, __fmul_rn(fj, cw))));
        int C1 = (int)floorf(__fmul_rn(64.0f, __fadd_rn(x0, __fmul_rn(__fadd_rn(fj, 1.0f), cw))));
        bool dc = (C1 <= C0);
        c1 = (dc && (C1 < 64)) ? C1 + 1 : C1;
        c0 = (dc && (C1 >= 64)) ? C0 - 1 : C0;
    } else {
        float by0 = (bank == 2) ? sy0 : oy0, by1 = (bank == 2) ? sy1 : oy1;
        float bx0 = (bank == 2) ? sx0 : ox0, bx1 = (bank == 2) ? sx1 : ox1;
        float uy0 = fminf(sy0, oy0), uy1 = fmaxf(sy1, oy1);
        float ux0 = fminf(sx0, ox0), ux1 = fmaxf(sx1, ox1);
        float ch = __fdiv_rn(__fsub_rn(uy1, uy0), 3.0f);
        float cw = __fdiv_rn(__fsub_rn(ux1, ux0), 3.0f);
        float ylo = __fadd_rn(uy0, __fmul_rn(fi, ch));
        float yhi = __fadd_rn(uy0, __fmul_rn(__fadd_rn(fi, 1.0f), ch));
        float xlo = __fadd_rn(ux0, __fmul_rn(fj, cw));
        float xhi = __fadd_rn(ux0, __fmul_rn(__fadd_rn(fj, 1.0f), cw));
        r0 = (int)floorf(__fmul_rn(64.0f, fmaxf(by0, ylo)));
        r1 = (int)floorf(__fmul_rn(64.0f, fminf(by1, yhi)));
        c0 = (int)floorf(__fmul_rn(64.0f, fmaxf(bx0, xlo)));
        c1 = (int)floorf(__fmul_rn(64.0f, fminf(bx1, xhi)));
    }
}

// ---------------------------------------------------------------------------
// Kernel 1: column-per-lane streaming with register column-prefix.
// Lane l owns column l. 64 coalesced row loads (256B/instr); run += x in a
// register; snapshot `run` to LDS ONLY at the <=24 needed boundary rows
// (uniform scalar branch on a readfirstlane'd 64-bit row mask). Eval: 36
// lanes sum snap[idx1][w]-snap[idx0][w] over their col range. ~85 LDS ops
// per plane vs 324 in the scan version -> HBM-bound.
// M layout: [plane][36] raw region SUMS (head divides by cnt).
// ---------------------------------------------------------------------------
__global__ __launch_bounds__(64, 4) void k_region_sums(const float* __restrict__ feat,
                                                       const float* __restrict__ bbox_s,
                                                       const float* __restrict__ bbox_o,
                                                       float* __restrict__ M) {
    int l = threadIdx.x;
    int pid0 = blockIdx.x * PLANES;
    int b = pid0 >> 8;

    float sy0 = bbox_s[b * 4 + 0], sy1 = bbox_s[b * 4 + 1];
    float sx0 = bbox_s[b * 4 + 2], sx1 = bbox_s[b * 4 + 3];
    float oy0 = bbox_o[b * 4 + 0], oy1 = bbox_o[b * 4 + 1];
    float ox0 = bbox_o[b * 4 + 2], ox1 = bbox_o[b * 4 + 3];

    int myb = l / 9, myrest = l % 9, myi = myrest / 3, myj = myrest % 3;

    // Build the union row mask over all 12 (bank,i) row-ranges (identical in
    // every lane), and capture this lane's own clamped row range.
    unsigned long long rowmask = 0ull;
    int my_r0c = 0, my_r1c = 0;
    #pragma unroll
    for (int bk = 0; bk < 4; ++bk) {
        #pragma unroll
        for (int i = 0; i < 3; ++i) {
            int r0, r1, c0, c1;
            region_bounds(bk, i, 0, sy0, sy1, sx0, sx1, oy0, oy1, ox0, ox1, r0, r1, c0, c1);
            int r0c = max(r0, 0), r1c = min(r1, 64);
            if (r1c >= 1) rowmask |= 1ull << (r1c - 1);
            if (r0c >= 1) rowmask |= 1ull << (r0c - 1);
            if (bk == myb && i == myi) { my_r0c = r0c; my_r1c = r1c; }
        }
    }
    // Force the mask into SGPRs so the per-row test is a scalar branch.
    unsigned int mlo = __builtin_amdgcn_readfirstlane((unsigned int)rowmask);
    unsigned int mhi = __builtin_amdgcn_readfirstlane((unsigned int)(rowmask >> 32));
    unsigned long long smask = (((unsigned long long)mhi) << 32) | mlo;

    // Per-lane eval parameters (lanes 0..35)
    int cl = 0, ch = 0, idx0 = ZROW, idx1 = ZROW;
    if (l < 36) {
        int r0, r1, c0, c1;
        region_bounds(myb, myi, myj, sy0, sy1, sx0, sx1, oy0, oy1, ox0, ox1, r0, r1, c0, c1);
        cl = max(c0, 0); ch = min(c1, 64);
        if (my_r1c <= my_r0c) {
            ch = cl;  // empty row range -> skip loop, s = 0
        } else {
            idx1 = __popcll(smask & ((1ull << (my_r1c - 1)) - 1ull));
            idx0 = (my_r0c > 0) ? (int)__popcll(smask & ((1ull << (my_r0c - 1)) - 1ull)) : ZROW;
        }
    }

    __shared__ float S[(ZROW + 1) * SSTR];
    S[ZROW * SSTR + l] = 0.0f;  // zero row for "no lower boundary"
    __syncthreads();

    const float* pf = feat + (size_t)pid0 * 4096 + l;
    for (int p = 0; p < PLANES; ++p) {
        // chunked register staging keeps VGPR pressure moderate while leaving
        // plenty of loads in flight
        float x[32];
        float run = 0.0f;
        int slot = 0;
        #pragma unroll
        for (int h = 0; h < 32; ++h) x[h] = pf[h * 64];
        #pragma unroll
        for (int h = 0; h < 32; ++h) {
            run += x[h];
            if ((smask >> h) & 1ull) { S[slot * SSTR + l] = run; ++slot; }
        }
        #pragma unroll
        for (int h = 0; h < 32; ++h) x[h] = pf[(32 + h) * 64];
        #pragma unroll
        for (int h = 0; h < 32; ++h) {
            run += x[h];
            if ((smask >> (32 + h)) & 1ull) { S[slot * SSTR + l] = run; ++slot; }
        }
        __syncthreads();

        if (l < 36) {
            float s = 0.0f;
            for (int w = cl; w < ch; ++w)
                s += S[idx1 * SSTR + w] - S[idx0 * SSTR + w];
            M[(size_t)(pid0 + p) * 36 + l] = s;
        }
        __syncthreads();
        pf += 4096;
    }
}

// ---------------------------------------------------------------------------
// Kernel 2: head. One block per b. Stage M[b] TRANSPOSED in LDS as
// MlT[36][264] so the 256-MAC dot reads contiguous float4 (ds_read_b128).
// 324 threads each dot 256 channels with conv_w row (float4), BN2 +
// zero-count mask (counts computed inline, bit-exact), fold 4 banks ->
// f[81], 81->40->9 MLP, predicate dot.
// ---------------------------------------------------------------------------
__global__ __launch_bounds__(384) void k_head(const float* __restrict__ M,
                                              const float* __restrict__ bbox_s,
                                              const float* __restrict__ bbox_o,
                                              const float* __restrict__ conv_w,
                                              const float* __restrict__ conv_b,
                                              const float* __restrict__ g2,
                                              const float* __restrict__ b2,
                                              const float* __restrict__ m2,
                                              const float* __restrict__ v2,
                                              const float* __restrict__ fc1_w,
                                              const float* __restrict__ fc1_b,
                                              const float* __restrict__ g1,
                                              const float* __restrict__ b1,
                                              const float* __restrict__ m1,
                                              const float* __restrict__ v1,
                                              const float* __restrict__ fc2_w,
                                              const float* __restrict__ fc2_b,
                                              const float* __restrict__ pred,
                                              float* __restrict__ out) {
    int b = blockIdx.x;
    int t = threadIdx.x;

    __shared__ float MlT[36 * 264];
    __shared__ float val[324];
    __shared__ float fv[81];
    __shared__ float hv[40];
    __shared__ float lg[9];

    // stage transposed: MlT[r][c] = M[b][c][r]
    for (int i = t; i < 36 * 256; i += 384) {
        int r = i >> 8, c = i & 255;
        MlT[r * 264 + c] = M[(size_t)b * (256 * 36) + c * 36 + r];
    }
    __syncthreads();

    if (t < 324) {
        int region = t / 9, k = t - region * 9;
        int bank = region / 9, ij = region - bank * 9;
        int ii = ij / 3, jj = ij % 3;
        int o = bank * 81 + ii * 27 + jj * 9 + k;

        float sy0 = bbox_s[b * 4 + 0], sy1 = bbox_s[b * 4 + 1];
        float sx0 = bbox_s[b * 4 + 2], sx1 = bbox_s[b * 4 + 3];
        float oy0 = bbox_o[b * 4 + 0], oy1 = bbox_o[b * 4 + 1];
        float ox0 = bbox_o[b * 4 + 2], ox1 = bbox_o[b * 4 + 3];
        int r0, r1, c0, c1;
        region_bounds(bank, ii, jj, sy0, sy1, sx0, sx1, oy0, oy1, ox0, ox1, r0, r1, c0, c1);
        int nrows = max(0, min(r1, 64) - max(r0, 0));
        int ncols = max(0, min(c1, 64) - max(c0, 0));
        float cnt = (float)(nrows * ncols);

        float v = 0.0f;
        if (cnt > 0.0f) {
            const float4* wv = (const float4*)(conv_w + o * 256);
            const float4* mv = (const float4*)(&MlT[region * 264]);
            float4 a4 = make_float4(0.f, 0.f, 0.f, 0.f);
            #pragma unroll 8
            for (int c4 = 0; c4 < 64; ++c4) {
                float4 wq = wv[c4], mq = mv[c4];
                a4.x += wq.x * mq.x; a4.y += wq.y * mq.y;
                a4.z += wq.z * mq.z; a4.w += wq.w * mq.w;
            }
            float dot = (a4.x + a4.y) + (a4.z + a4.w);
            float mean = dot / cnt;
            float sc = g2[o] / sqrtf(v2[o] + EPSF);
            v = (mean + conv_b[o] - m2[o]) * sc + b2[o];
        }
        val[region * 9 + k] = v;
    }
    __syncthreads();

    if (t < 81) {
        int k = t / 9, ij = t - k * 9;
        fv[t] = val[(0 + ij) * 9 + k] + val[(9 + ij) * 9 + k] +
                val[(18 + ij) * 9 + k] + val[(27 + ij) * 9 + k];
    }
    __syncthreads();

    if (t < 40) {
        float h = fc1_b[t];
        for (int u = 0; u < 81; ++u) h += fv[u] * fc1_w[t * 81 + u];
        h = (h - m1[t]) * (g1[t] / sqrtf(v1[t] + EPSF)) + b1[t];
        hv[t] = h;
    }
    __syncthreads();

    if (t < 9) {
        float lgt = fc2_b[t];
        for (int u = 0; u < 40; ++u) lgt += hv[u] * fc2_w[t * 40 + u];
        lg[t] = lgt * pred[b * 9 + t];
    }
    __syncthreads();

    if (t == 0) {
        float s = 0.0f;
        for (int i = 0; i < 9; ++i) s += lg[i];
        out[b] = s;
    }
}

extern "C" void kernel_launch(void* const* d_in, const int* in_sizes, int n_in,
                              void* d_out, int out_size, void* d_ws, size_t ws_size,
                              hipStream_t stream) {
    const float* feat   = (const float*)d_in[0];
    const float* bbox_s = (const float*)d_in[1];
    const float* bbox_o = (const float*)d_in[2];
    const float* pred   = (const float*)d_in[3];
    const float* conv_w = (const float*)d_in[4];
    const float* conv_b = (const float*)d_in[5];
    const float* g2     = (const float*)d_in[6];
    const float* b2     = (const float*)d_in[7];
    const float* m2     = (const float*)d_in[8];
    const float* v2     = (const float*)d_in[9];
    const float* fc1_w  = (const float*)d_in[10];
    const float* fc1_b  = (const float*)d_in[11];
    const float* g1     = (const float*)d_in[12];
    const float* b1     = (const float*)d_in[13];
    const float* m1     = (const float*)d_in[14];
    const float* v1     = (const float*)d_in[15];
    const float* fc2_w  = (const float*)d_in[16];
    const float* fc2_b  = (const float*)d_in[17];
    float* out = (float*)d_out;

    float* M = (float*)d_ws;  // 64*256*36*4 = 2359296 B

    k_region_sums<<<(BB * CC) / PLANES, 64, 0, stream>>>(feat, bbox_s, bbox_o, M);
    k_head<<<BB, 384, 0, stream>>>(M, bbox_s, bbox_o, conv_w, conv_b, g2, b2, m2, v2,
                                   fc1_w, fc1_b, g1, b1, m1, v1, fc2_w, fc2_b,
                                   pred, out);
}

// Round 4
// 54.749 us; speedup vs baseline: 1.1883x; 1.1510x over previous
//
#include <hip/hip_runtime.h>
#include <hip/hip_bf16.h>
#include <cstdint>

#define BB 64
#define CC 256
#define EPSF 1e-5f
#define PLANES 4
#define ZROW 24
#define SSTR 65        // snapshot row stride (65 mod 32 = 1 -> conflict-free)
#define NPLANES (BB * CC)

// ---------------------------------------------------------------------------
// Bit-exact replication of the reference float32 bound arithmetic for ONE
// (bank, i, j) cell. No FMA contraction (__f*_rn), floorf, int32 truncation.
// Row bounds depend only on i; col bounds only on j.
// bank 0 = subj(bbox_s), 1 = subj(bbox_o), 2 = joint(clip s), 3 = joint(clip o)
// ---------------------------------------------------------------------------
__device__ __forceinline__ void region_bounds(int bank, int i, int j,
                                              float sy0, float sy1, float sx0, float sx1,
                                              float oy0, float oy1, float ox0, float ox1,
                                              int& r0, int& r1, int& c0, int& c1) {
    float fi = (float)i, fj = (float)j;
    if (bank < 2) {
        float y0 = bank ? oy0 : sy0, y1 = bank ? oy1 : sy1;
        float x0 = bank ? ox0 : sx0, x1 = bank ? ox1 : sx1;
        float ch = __fdiv_rn(__fsub_rn(y1, y0), 3.0f);
        float cw = __fdiv_rn(__fsub_rn(x1, x0), 3.0f);
        int R0 = (int)floorf(__fmul_rn(64.0f, __fadd_rn(y0, __fmul_rn(fi, ch))));
        int R1 = (int)floorf(__fmul_rn(64.0f, __fadd_rn(y0, __fmul_rn(__fadd_rn(fi, 1.0f), ch))));
        bool dr = (R1 <= R0);
        r1 = (dr && (R1 < 63)) ? R1 + 1 : R1;
        r0 = (dr && (R1 >= 63)) ? R0 - 1 : R0;
        int C0 = (int)floorf(__fmul_rn(64.0f, __fadd_rn(x0, __fmul_rn(fj, cw))));
        int C1 = (int)floorf(__fmul_rn(64.0f, __fadd_rn(x0, __fmul_rn(__fadd_rn(fj, 1.0f), cw))));
        bool dc = (C1 <= C0);
        c1 = (dc && (C1 < 64)) ? C1 + 1 : C1;
        c0 = (dc && (C1 >= 64)) ? C0 - 1 : C0;
    } else {
        float by0 = (bank == 2) ? sy0 : oy0, by1 = (bank == 2) ? sy1 : oy1;
        float bx0 = (bank == 2) ? sx0 : ox0, bx1 = (bank == 2) ? sx1 : ox1;
        float uy0 = fminf(sy0, oy0), uy1 = fmaxf(sy1, oy1);
        float ux0 = fminf(sx0, ox0), ux1 = fmaxf(sx1, ox1);
        float ch = __fdiv_rn(__fsub_rn(uy1, uy0), 3.0f);
        float cw = __fdiv_rn(__fsub_rn(ux1, ux0), 3.0f);
        float ylo = __fadd_rn(uy0, __fmul_rn(fi, ch));
        float yhi = __fadd_rn(uy0, __fmul_rn(__fadd_rn(fi, 1.0f), ch));
        float xlo = __fadd_rn(ux0, __fmul_rn(fj, cw));
        float xhi = __fadd_rn(ux0, __fmul_rn(__fadd_rn(fj, 1.0f), cw));
        r0 = (int)floorf(__fmul_rn(64.0f, fmaxf(by0, ylo)));
        r1 = (int)floorf(__fmul_rn(64.0f, fminf(by1, yhi)));
        c0 = (int)floorf(__fmul_rn(64.0f, fmaxf(bx0, xlo)));
        c1 = (int)floorf(__fmul_rn(64.0f, fminf(bx1, xhi)));
    }
}

// ---------------------------------------------------------------------------
// Kernel 1: column-per-lane streaming, register column-prefix, and NEEDED-ROW
// MASKING: rows outside the union of the 12 region row-intervals are never
// loaded (uniform scalar branch, no VMEM); columns outside the col-union are
// exec-masked off (coalescer fetches only union lines). Gap rows cancel in
// prefix differences, so skipping them is exact.
// M layout: [region 36][plane 16384] for coalesced head reads.
// ---------------------------------------------------------------------------
__global__ __launch_bounds__(64, 4) void k_region_sums(const float* __restrict__ feat,
                                                       const float* __restrict__ bbox_s,
                                                       const float* __restrict__ bbox_o,
                                                       float* __restrict__ M) {
    int l = threadIdx.x;
    int pid0 = blockIdx.x * PLANES;
    int b = pid0 >> 8;

    float sy0 = bbox_s[b * 4 + 0], sy1 = bbox_s[b * 4 + 1];
    float sx0 = bbox_s[b * 4 + 2], sx1 = bbox_s[b * 4 + 3];
    float oy0 = bbox_o[b * 4 + 0], oy1 = bbox_o[b * 4 + 1];
    float ox0 = bbox_o[b * 4 + 2], ox1 = bbox_o[b * 4 + 3];

    int myb = l / 9, rest = l % 9, myi = rest / 3, myj = rest % 3;

    unsigned long long needm = 0ull, snapm = 0ull;
    int my_r0c = 0, my_r1c = 0, mycl = 0, mych = 0;
    bool colact = false;
    #pragma unroll
    for (int bk = 0; bk < 4; ++bk) {
        #pragma unroll
        for (int idx = 0; idx < 3; ++idx) {
            int r0, r1, c0, c1;
            region_bounds(bk, idx, idx, sy0, sy1, sx0, sx1, oy0, oy1, ox0, ox1,
                          r0, r1, c0, c1);
            int r0c = max(r0, 0), r1c = min(r1, 64);
            if (r1c > r0c) {
                unsigned long long hi = (r1c >= 64) ? ~0ull : ((1ull << r1c) - 1ull);
                unsigned long long lo = (1ull << r0c) - 1ull;
                needm |= hi ^ lo;
                snapm |= 1ull << (r1c - 1);
                if (r0c >= 1) snapm |= 1ull << (r0c - 1);
            }
            int clc = max(c0, 0), chc = min(c1, 64);
            if (chc > clc) colact = colact || (l >= clc && l < chc);
            if (bk == myb && idx == myi) { my_r0c = r0c; my_r1c = r1c; }
            if (bk == myb && idx == myj) { mycl = max(c0, 0); mych = min(c1, 64); }
        }
    }
    // Force masks into SGPRs -> per-row tests are scalar branches.
    {
        unsigned int a = __builtin_amdgcn_readfirstlane((unsigned int)needm);
        unsigned int bm = __builtin_amdgcn_readfirstlane((unsigned int)(needm >> 32));
        needm = (((unsigned long long)bm) << 32) | a;
        unsigned int c = __builtin_amdgcn_readfirstlane((unsigned int)snapm);
        unsigned int d = __builtin_amdgcn_readfirstlane((unsigned int)(snapm >> 32));
        snapm = (((unsigned long long)d) << 32) | c;
    }

    // Per-lane eval parameters (lanes 0..35)
    int cl = 0, chx = 0, idx0 = ZROW, idx1 = ZROW;
    if (l < 36) {
        cl = mycl; chx = mych;
        if (my_r1c <= my_r0c) {
            chx = cl;  // empty row range -> s = 0
        } else {
            idx1 = (int)__popcll(snapm & ((1ull << (my_r1c - 1)) - 1ull));
            idx0 = (my_r0c > 0) ? (int)__popcll(snapm & ((1ull << (my_r0c - 1)) - 1ull))
                                : ZROW;
        }
    }

    __shared__ float S[(ZROW + 1) * SSTR];
    S[ZROW * SSTR + l] = 0.0f;  // zero row for "no lower boundary"
    __syncthreads();

    const float* pf = feat + (size_t)pid0 * 4096 + l;
    for (int p = 0; p < PLANES; ++p) {
        float x[32];
        float run = 0.0f;
        int slot = 0;

        #pragma unroll
        for (int h = 0; h < 32; ++h) {
            float v = 0.0f;
            if (((needm >> h) & 1ull) && colact) v = pf[h * 64];
            x[h] = v;
        }
        #pragma unroll
        for (int h = 0; h < 32; ++h) {
            if ((needm >> h) & 1ull) run += x[h];
            if ((snapm >> h) & 1ull) { S[slot * SSTR + l] = run; ++slot; }
        }
        #pragma unroll
        for (int h = 0; h < 32; ++h) {
            float v = 0.0f;
            if (((needm >> (h + 32)) & 1ull) && colact) v = pf[(h + 32) * 64];
            x[h] = v;
        }
        #pragma unroll
        for (int h = 0; h < 32; ++h) {
            if ((needm >> (h + 32)) & 1ull) run += x[h];
            if ((snapm >> (h + 32)) & 1ull) { S[slot * SSTR + l] = run; ++slot; }
        }
        __syncthreads();

        if (l < 36) {
            float s = 0.0f;
            for (int w = cl; w < chx; ++w)
                s += S[idx1 * SSTR + w] - S[idx0 * SSTR + w];
            M[(size_t)l * NPLANES + pid0 + p] = s;
        }
        __syncthreads();
        pf += 4096;
    }
}

// ---------------------------------------------------------------------------
// Kernel 2a: dot. One block per (b, bank) -> 256 blocks, full CU coverage.
// Stage this bank's 9 region rows of M (coalesced from [36][16384] layout),
// 81 threads each dot 256 channels with conv_w (float4), BN2 + count mask.
// val layout: [b][bank][ij][k]  (b*324 + bank*81 + ij*9 + k)
// ---------------------------------------------------------------------------
__global__ __launch_bounds__(128) void k_head_dot(const float* __restrict__ M,
                                                  const float* __restrict__ bbox_s,
                                                  const float* __restrict__ bbox_o,
                                                  const float* __restrict__ conv_w,
                                                  const float* __restrict__ conv_b,
                                                  const float* __restrict__ g2,
                                                  const float* __restrict__ b2,
                                                  const float* __restrict__ m2,
                                                  const float* __restrict__ v2,
                                                  float* __restrict__ val) {
    int blk = blockIdx.x;
    int b = blk >> 2, bank = blk & 3;
    int t = threadIdx.x;

    __shared__ float MlT9[9 * 264];
    for (int i = t; i < 9 * 256; i += 128) {
        int ij = i >> 8, c = i & 255;
        MlT9[ij * 264 + c] = M[(size_t)(bank * 9 + ij) * NPLANES + (b << 8) + c];
    }
    __syncthreads();

    if (t < 81) {
        int ij = t / 9, k = t - ij * 9;
        int ii = ij / 3, jj = ij % 3;
        int o = bank * 81 + ii * 27 + jj * 9 + k;

        float sy0 = bbox_s[b * 4 + 0], sy1 = bbox_s[b * 4 + 1];
        float sx0 = bbox_s[b * 4 + 2], sx1 = bbox_s[b * 4 + 3];
        float oy0 = bbox_o[b * 4 + 0], oy1 = bbox_o[b * 4 + 1];
        float ox0 = bbox_o[b * 4 + 2], ox1 = bbox_o[b * 4 + 3];
        int r0, r1, c0, c1;
        region_bounds(bank, ii, jj, sy0, sy1, sx0, sx1, oy0, oy1, ox0, ox1,
                      r0, r1, c0, c1);
        int nrows = max(0, min(r1, 64) - max(r0, 0));
        int ncols = max(0, min(c1, 64) - max(c0, 0));
        float cnt = (float)(nrows * ncols);

        float v = 0.0f;
        if (cnt > 0.0f) {
            const float4* wv = (const float4*)(conv_w + o * 256);
            const float4* mv = (const float4*)(&MlT9[ij * 264]);
            float4 a4 = make_float4(0.f, 0.f, 0.f, 0.f);
            #pragma unroll 8
            for (int c4 = 0; c4 < 64; ++c4) {
                float4 wq = wv[c4], mq = mv[c4];
                a4.x += wq.x * mq.x; a4.y += wq.y * mq.y;
                a4.z += wq.z * mq.z; a4.w += wq.w * mq.w;
            }
            float dot = (a4.x + a4.y) + (a4.z + a4.w);
            float mean = dot / cnt;
            float sc = g2[o] / sqrtf(v2[o] + EPSF);
            v = (mean + conv_b[o] - m2[o]) * sc + b2[o];
        }
        val[b * 324 + bank * 81 + t] = v;
    }
}

// ---------------------------------------------------------------------------
// Kernel 2b: fold banks + tiny MLP + predicate dot. One block per b.
// ---------------------------------------------------------------------------
__global__ __launch_bounds__(128) void k_head_mlp(const float* __restrict__ val,
                                                  const float* __restrict__ fc1_w,
                                                  const float* __restrict__ fc1_b,
                                                  const float* __restrict__ g1,
                                                  const float* __restrict__ b1,
                                                  const float* __restrict__ m1,
                                                  const float* __restrict__ v1,
                                                  const float* __restrict__ fc2_w,
                                                  const float* __restrict__ fc2_b,
                                                  const float* __restrict__ pred,
                                                  float* __restrict__ out) {
    int b = blockIdx.x;
    int t = threadIdx.x;

    __shared__ float fv[81];
    __shared__ float hv[40];
    __shared__ float lg[9];

    if (t < 81) {
        int k = t / 9, ij = t - k * 9;
        const float* vb = val + b * 324;
        fv[t] = vb[0 * 81 + ij * 9 + k] + vb[1 * 81 + ij * 9 + k] +
                vb[2 * 81 + ij * 9 + k] + vb[3 * 81 + ij * 9 + k];
    }
    __syncthreads();

    if (t < 40) {
        float h = fc1_b[t];
        for (int u = 0; u < 81; ++u) h += fv[u] * fc1_w[t * 81 + u];
        h = (h - m1[t]) * (g1[t] / sqrtf(v1[t] + EPSF)) + b1[t];
        hv[t] = h;
    }
    __syncthreads();

    if (t < 9) {
        float lgt = fc2_b[t];
        for (int u = 0; u < 40; ++u) lgt += hv[u] * fc2_w[t * 40 + u];
        lg[t] = lgt * pred[b * 9 + t];
    }
    __syncthreads();

    if (t == 0) {
        float s = 0.0f;
        for (int i = 0; i < 9; ++i) s += lg[i];
        out[b] = s;
    }
}

extern "C" void kernel_launch(void* const* d_in, const int* in_sizes, int n_in,
                              void* d_out, int out_size, void* d_ws, size_t ws_size,
                              hipStream_t stream) {
    const float* feat   = (const float*)d_in[0];
    const float* bbox_s = (const float*)d_in[1];
    const float* bbox_o = (const float*)d_in[2];
    const float* pred   = (const float*)d_in[3];
    const float* conv_w = (const float*)d_in[4];
    const float* conv_b = (const float*)d_in[5];
    const float* g2     = (const float*)d_in[6];
    const float* b2     = (const float*)d_in[7];
    const float* m2     = (const float*)d_in[8];
    const float* v2     = (const float*)d_in[9];
    const float* fc1_w  = (const float*)d_in[10];
    const float* fc1_b  = (const float*)d_in[11];
    const float* g1     = (const float*)d_in[12];
    const float* b1     = (const float*)d_in[13];
    const float* m1     = (const float*)d_in[14];
    const float* v1     = (const float*)d_in[15];
    const float* fc2_w  = (const float*)d_in[16];
    const float* fc2_b  = (const float*)d_in[17];
    float* out = (float*)d_out;

    char* ws = (char*)d_ws;
    float* M   = (float*)ws;                       // 36*16384*4 = 2359296 B
    float* val = (float*)(ws + 2359296);           // 64*324*4   =   82944 B

    k_region_sums<<<(BB * CC) / PLANES, 64, 0, stream>>>(feat, bbox_s, bbox_o, M);
    k_head_dot<<<BB * 4, 128, 0, stream>>>(M, bbox_s, bbox_o, conv_w, conv_b,
                                           g2, b2, m2, v2, val);
    k_head_mlp<<<BB, 128, 0, stream>>>(val, fc1_w, fc1_b, g1, b1, m1, v1,
                                       fc2_w, fc2_b, pred, out);
}